// Round 4
// baseline (1219.390 us; speedup 1.0000x reference)
//
#include <hip/hip_runtime.h>
#include <cstddef>

typedef _Float16 f16x4 __attribute__((ext_vector_type(4)));
typedef float f32x4 __attribute__((ext_vector_type(4)));

__device__ __forceinline__ f32x4 mfma16(f16x4 a, f16x4 b, f32x4 c) {
  return __builtin_amdgcn_mfma_f32_16x16x16f16(a, b, c, 0, 0, 0);
}

// Q is pre-scaled by 0.25 * log2(e) so softmax weights are exp2(score).
#define QSCALE (0.25f * 1.44269504f)

// ---------------------------------------------------------------------------
// init node embedding: out[n][o] = b[o] + sum_k in[n][k] * W[k][o]
// ---------------------------------------------------------------------------
__global__ __launch_bounds__(256) void init_embed_kernel(
    const float* __restrict__ in, const float* __restrict__ W,
    const float* __restrict__ b, float* __restrict__ out, int N, int Kin)
{
  int idx = blockIdx.x * 256 + threadIdx.x;
  if (idx >= N * 64) return;
  int n = idx >> 6, o = idx & 63;
  float acc = b[o];
  const float* row = in + (size_t)n * Kin;
  for (int k = 0; k < Kin; k++) acc += row[k] * W[k * 64 + o];
  out[idx] = acc;
}

// ---------------------------------------------------------------------------
// GINE message + aggregate: agg[dst] += relu(x[src] + (attr @ We + be))
// one wave per edge (64 lanes = 64 dims)
// ---------------------------------------------------------------------------
__global__ __launch_bounds__(256) void gine_msg_kernel(
    const float* __restrict__ x, const float* __restrict__ attr,
    const float* __restrict__ We, const float* __restrict__ be,
    const int* __restrict__ ei, float* __restrict__ agg, int E)
{
  int idx = blockIdx.x * 256 + threadIdx.x;
  if (idx >= E * 64) return;
  int e = idx >> 6, d = idx & 63;
  int src = ei[e];
  int dst = ei[E + e];
  float ea = be[d];
  const float* arow = attr + (size_t)e * 10;
  #pragma unroll
  for (int k = 0; k < 10; k++) ea += arow[k] * We[k * 64 + d];
  float m = x[(size_t)src * 64 + d] + ea;
  m = fmaxf(m, 0.f);
  atomicAdd(&agg[(size_t)dst * 64 + d], m);
}

// ---------------------------------------------------------------------------
// GINE node MLP, fused: out = relu( relu((x+agg)@W1 + B1) @ W2 + B2 )
// ---------------------------------------------------------------------------
__global__ __launch_bounds__(256) void gine_mlp_kernel(
    const float* __restrict__ x, const float* __restrict__ agg,
    const float* __restrict__ W1, const float* __restrict__ B1,
    const float* __restrict__ W2, const float* __restrict__ B2,
    float* __restrict__ out, int N)
{
  __shared__ __align__(16) float sW1[64 * 64];
  __shared__ __align__(16) float sW2[64 * 64];
  __shared__ __align__(16) float sBuf[64 * 68];
  int t = threadIdx.x;
  int n0 = blockIdx.x * 64;
  #pragma unroll
  for (int i = 0; i < 16; i++) { int f = t + i * 256; sW1[f] = W1[f]; sW2[f] = W2[f]; }
  #pragma unroll
  for (int i = 0; i < 16; i++) {
    int f = t + i * 256;
    size_t g = (size_t)n0 * 64 + f;
    sBuf[(f >> 6) * 68 + (f & 63)] = x[g] + agg[g];
  }
  __syncthreads();
  int n = t >> 2, kk = t & 3;
  float acc[16];
  #pragma unroll
  for (int j = 0; j < 16; j++) acc[j] = B1[kk * 16 + j];
  #pragma unroll
  for (int d = 0; d < 64; d++) {
    float xv = sBuf[n * 68 + d];
    const float* wrow = &sW1[d * 64 + kk * 16];
    #pragma unroll
    for (int j = 0; j < 16; j++) acc[j] += xv * wrow[j];
  }
  __syncthreads();
  #pragma unroll
  for (int j = 0; j < 16; j++) sBuf[n * 68 + kk * 16 + j] = fmaxf(acc[j], 0.f);
  __syncthreads();
  #pragma unroll
  for (int j = 0; j < 16; j++) acc[j] = B2[kk * 16 + j];
  #pragma unroll
  for (int d = 0; d < 64; d++) {
    float xv = sBuf[n * 68 + d];
    const float* wrow = &sW2[d * 64 + kk * 16];
    #pragma unroll
    for (int j = 0; j < 16; j++) acc[j] += xv * wrow[j];
  }
  float* op = out + (size_t)(n0 + n) * 64 + kk * 16;
  #pragma unroll
  for (int j = 0; j < 16; j++) op[j] = fmaxf(acc[j], 0.f);
}

// ---------------------------------------------------------------------------
// Fused QKV projection. Stages the 64-node input tile once, then 3 weight
// phases. Q,K -> fp16 head-major [h][n][16] (Q scaled by QSCALE);
// V -> fp16 transposed [h][16][N].
// ---------------------------------------------------------------------------
__global__ __launch_bounds__(256) void proj_qkv_kernel(
    const float* __restrict__ xin,
    const float* __restrict__ Wq, const float* __restrict__ bq,
    const float* __restrict__ Wk, const float* __restrict__ bk,
    const float* __restrict__ Wv, const float* __restrict__ bv,
    _Float16* __restrict__ Qo, _Float16* __restrict__ Ko,
    _Float16* __restrict__ Vto, int N)
{
  __shared__ __align__(16) float sW[64 * 64];
  __shared__ __align__(16) float sIn[64 * 68];
  int t = threadIdx.x;
  int n0 = blockIdx.x * 64;
  #pragma unroll
  for (int i = 0; i < 16; i++) {
    int f = t + i * 256;
    sIn[(f >> 6) * 68 + (f & 63)] = xin[(size_t)n0 * 64 + f];
  }
  int n = t >> 2, kk = t & 3;
  const float* Ws[3] = {Wq, Wk, Wv};
  const float* bs[3] = {bq, bk, bv};
  for (int p = 0; p < 3; p++) {
    __syncthreads();   // also covers sIn staging on p==0; protects sW reuse
    #pragma unroll
    for (int i = 0; i < 16; i++) { int f = t + i * 256; sW[f] = Ws[p][f]; }
    __syncthreads();
    float acc[16];
    #pragma unroll
    for (int j = 0; j < 16; j++) acc[j] = bs[p][kk * 16 + j];
    #pragma unroll
    for (int d = 0; d < 64; d++) {
      float xv = sIn[n * 68 + d];
      const float* wrow = &sW[d * 64 + kk * 16];
      #pragma unroll
      for (int j = 0; j < 16; j++) acc[j] += xv * wrow[j];
    }
    if (p == 2) {
      #pragma unroll
      for (int j = 0; j < 16; j++)
        Vto[((size_t)kk * 16 + j) * N + (n0 + n)] = (_Float16)acc[j];
    } else {
      float scale = (p == 0) ? QSCALE : 1.0f;
      _Float16 tmp[16];
      #pragma unroll
      for (int j = 0; j < 16; j++) tmp[j] = (_Float16)(acc[j] * scale);
      _Float16* base = (p == 0) ? Qo : Ko;
      float4* dst = (float4*)(base + ((size_t)kk * N + n0 + n) * 16);
      dst[0] = ((float4*)tmp)[0];
      dst[1] = ((float4*)tmp)[1];
    }
  }
}

// ---------------------------------------------------------------------------
// MFMA flash cross-attention, no-max softmax (scores bounded; Q pre-scaled
// so weights are exp2(score), clamped at 14 to keep f16 P finite).
// Q,K: fp16 [H][N][16]; Vt: fp16 [H][16][N]; out: fp32 [Nq][64].
// Block = 16 queries x 1 head, 4 waves; wave w owns key chunks w*64+256*i.
// Scores computed transposed (D[key][q]) so exp2(D) feeds the PV MFMA's
// B operand directly. Per-lane partial l accumulated; single LDS combine.
// ---------------------------------------------------------------------------
__global__ __launch_bounds__(256) void attn_mfma_kernel(
    const _Float16* __restrict__ Q, const _Float16* __restrict__ K,
    const _Float16* __restrict__ Vt, float* __restrict__ out, int Nq, int Nk)
{
  const int h = blockIdx.y;
  const int q0 = blockIdx.x * 16;
  const int t = threadIdx.x;
  const int wave = t >> 6, lane = t & 63;
  const int l16 = lane & 15, quad = lane >> 4;

  // Q B-frag: B[k=d=quad*4+i][n=q=l16]
  const f16x4 qf = *(const f16x4*)(Q + ((size_t)h * Nq + q0 + l16) * 16 + quad * 4);
  const _Float16* Kh = K + (size_t)h * Nk * 16;
  const _Float16* Vh = Vt + ((size_t)h * 16 + l16) * Nk;

  f32x4 oacc = {0.f, 0.f, 0.f, 0.f};
  float lacc = 0.f;
  const f32x4 zero = {0.f, 0.f, 0.f, 0.f};

  for (int kb = wave * 64; kb < Nk; kb += 256) {
    f16x4 kf[4], vf[4];
    #pragma unroll
    for (int c = 0; c < 4; c++) {
      // K A-frag: A[m=key=l16][k=d=quad*4+i]
      kf[c] = *(const f16x4*)(Kh + (size_t)(kb + c * 16 + l16) * 16 + quad * 4);
      // V^T A-frag: A[m=d=l16][k=key=quad*4+i]
      vf[c] = *(const f16x4*)(Vh + kb + c * 16 + quad * 4);
    }
    f32x4 s[4];
    #pragma unroll
    for (int c = 0; c < 4; c++) s[c] = mfma16(kf[c], qf, zero);

    f16x4 pf[4];
    #pragma unroll
    for (int c = 0; c < 4; c++)
      #pragma unroll
      for (int r = 0; r < 4; r++) {
        float p = exp2f(fminf(s[c][r], 14.f));
        lacc += p;
        pf[c][r] = (_Float16)p;
      }
    // PV: O^T += V^T-chunk * P^T-chunk  (pf IS the B-frag already)
    #pragma unroll
    for (int c = 0; c < 4; c++) oacc = mfma16(vf[c], pf[c], oacc);
  }

  // combine: sum O and l over 4 waves (and l over 4 quads)
  __shared__ float sO[4][16][16];
  __shared__ float sl[4][4][16];
  #pragma unroll
  for (int r = 0; r < 4; r++) sO[wave][quad * 4 + r][l16] = oacc[r];
  sl[wave][quad][l16] = lacc;
  __syncthreads();
  {
    int q = t >> 4, d = t & 15;
    float O = 0.f, L = 0.f;
    #pragma unroll
    for (int w = 0; w < 4; w++) {
      O += sO[w][d][q];
      #pragma unroll
      for (int qd = 0; qd < 4; qd++) L += sl[w][qd][q];
    }
    out[(size_t)(q0 + q) * 64 + h * 16 + d] = O / L;
  }
}

// ---------------------------------------------------------------------------
// LayerNorm(h + a) * g + b
// ---------------------------------------------------------------------------
__global__ __launch_bounds__(256) void ln_add_kernel(
    const float* __restrict__ h, const float* __restrict__ a,
    const float* __restrict__ g, const float* __restrict__ bb,
    float* __restrict__ out, int N)
{
  int idx = blockIdx.x * 256 + threadIdx.x;
  if (idx >= N * 64) return;
  int d = idx & 63;
  float v = h[idx] + a[idx];
  float sm = v;
  #pragma unroll
  for (int o = 1; o < 64; o <<= 1) sm += __shfl_xor(sm, o);
  float mu = sm * 0.015625f;
  float c = v - mu;
  float q = c * c;
  #pragma unroll
  for (int o = 1; o < 64; o <<= 1) q += __shfl_xor(q, o);
  float var = q * 0.015625f;
  out[idx] = c * rsqrtf(var + 1e-5f) * g[d] + bb[d];
}

// ---------------------------------------------------------------------------
// segment-sum pooling
// ---------------------------------------------------------------------------
__global__ __launch_bounds__(256) void pool_acc_kernel(
    const float* __restrict__ x, const int* __restrict__ batch,
    float* __restrict__ sums, float* __restrict__ cnt, int N, int colOff, int cntOff)
{
  int idx = blockIdx.x * 256 + threadIdx.x;
  if (idx >= N * 64) return;
  int n = idx >> 6, d = idx & 63;
  int seg = batch[n];
  atomicAdd(&sums[seg * 128 + colOff + d], x[idx]);
  if (d == 0) atomicAdd(&cnt[cntOff + seg], 1.0f);
}

// ---------------------------------------------------------------------------
// final head
// ---------------------------------------------------------------------------
__global__ __launch_bounds__(256) void final_kernel(
    const float* __restrict__ sums, const float* __restrict__ cnt,
    const float* __restrict__ fc1w, const float* __restrict__ fc1b,
    const float* __restrict__ fc2w, const float* __restrict__ fc2b,
    float* __restrict__ out)
{
  __shared__ float z[32 * 128];
  __shared__ float h1[32 * 64];
  int t = threadIdx.x;
  for (int f = t; f < 32 * 128; f += 256) {
    int s = f >> 7, j = f & 127;
    float c = cnt[(j >> 6) * 32 + s];
    z[f] = sums[f] / fmaxf(c, 1.f);
  }
  __syncthreads();
  for (int f = t; f < 32 * 64; f += 256) {
    int s = f >> 6, o = f & 63;
    float acc = fc1b[o];
    for (int j = 0; j < 128; j++) acc += z[s * 128 + j] * fc1w[j * 64 + o];
    h1[f] = fmaxf(acc, 0.f);
  }
  __syncthreads();
  if (t < 32) {
    float acc = fc2b[0];
    for (int o = 0; o < 64; o++) acc += h1[t * 64 + o] * fc2w[o];
    out[t] = 1.f / (1.f + __expf(-acc));
  }
}

// ---------------------------------------------------------------------------
extern "C" void kernel_launch(void* const* d_in, const int* in_sizes, int n_in,
                              void* d_out, int out_size, void* d_ws, size_t ws_size,
                              hipStream_t stream)
{
  (void)in_sizes; (void)n_in; (void)out_size; (void)ws_size;
  const float* mol_x          = (const float*)d_in[0];
  const float* prot_x         = (const float*)d_in[1];
  const float* mol_edge_attr  = (const float*)d_in[2];
  const float* prot_edge_attr = (const float*)d_in[3];
  const float* inm_w = (const float*)d_in[4];
  const float* inm_b = (const float*)d_in[5];
  const float* inp_w = (const float*)d_in[6];
  const float* inp_b = (const float*)d_in[7];
  const float* iem_w = (const float*)d_in[8];
  const float* iem_b = (const float*)d_in[9];
  const float* iep_w = (const float*)d_in[10];
  const float* iep_b = (const float*)d_in[11];
  const float* gm_w1 = (const float*)d_in[12];
  const float* gm_b1 = (const float*)d_in[13];
  const float* gm_w2 = (const float*)d_in[14];
  const float* gm_b2 = (const float*)d_in[15];
  const float* gp_w1 = (const float*)d_in[16];
  const float* gp_b1 = (const float*)d_in[17];
  const float* gp_w2 = (const float*)d_in[18];
  const float* gp_b2 = (const float*)d_in[19];
  const float* m2p_w = (const float*)d_in[20];
  const float* m2p_b = (const float*)d_in[21];
  const float* p2m_w = (const float*)d_in[22];
  const float* p2m_b = (const float*)d_in[23];
  const float* lnm_g = (const float*)d_in[24];
  const float* lnm_b = (const float*)d_in[25];
  const float* lnp_g = (const float*)d_in[26];
  const float* lnp_b = (const float*)d_in[27];
  const float* fc1_w = (const float*)d_in[28];
  const float* fc1_b = (const float*)d_in[29];
  const float* fc2_w = (const float*)d_in[30];
  const float* fc2_b = (const float*)d_in[31];
  const int* mol_ei     = (const int*)d_in[32];
  const int* prot_ei    = (const int*)d_in[33];
  const int* mol_batch  = (const int*)d_in[34];
  const int* prot_batch = (const int*)d_in[35];

  const int NM = 4096, NP = 8192, EM = 65536, EP = 262144;

  float* ws = (float*)d_ws;
  size_t off = 0;
  auto nxt  = [&](size_t n) { float* p = ws + off; off += n; return p; };
  auto nxtH = [&](size_t n) { _Float16* p = (_Float16*)(ws + off); off += (n + 1) / 2; return p; };
  float* x_mol    = nxt((size_t)NM * 64);
  float* x_prot   = nxt((size_t)NP * 64);
  float* agg_mol  = nxt((size_t)NM * 64);
  float* agg_prot = nxt((size_t)NP * 64);
  float* h_mol    = nxt((size_t)NM * 64);
  float* h_prot   = nxt((size_t)NP * 64);
  float* a_mol    = nxt((size_t)NM * 64);
  float* a_prot   = nxt((size_t)NP * 64);
  _Float16* Qm  = nxtH((size_t)NM * 64);
  _Float16* Km  = nxtH((size_t)NM * 64);
  _Float16* Vtm = nxtH((size_t)NM * 64);
  _Float16* Qp  = nxtH((size_t)NP * 64);
  _Float16* Kp  = nxtH((size_t)NP * 64);
  _Float16* Vtp = nxtH((size_t)NP * 64);
  float* pool = nxt(32 * 128);
  float* cnt  = nxt(64);

  init_embed_kernel<<<NM * 64 / 256, 256, 0, stream>>>(mol_x, inm_w, inm_b, x_mol, NM, 11);
  init_embed_kernel<<<NP * 64 / 256, 256, 0, stream>>>(prot_x, inp_w, inp_b, x_prot, NP, 15);

  for (int l = 0; l < 3; l++) {
    (void)hipMemsetAsync(agg_mol, 0, (size_t)NM * 64 * 4, stream);
    (void)hipMemsetAsync(agg_prot, 0, (size_t)NP * 64 * 4, stream);
    gine_msg_kernel<<<EM * 64 / 256, 256, 0, stream>>>(x_mol, mol_edge_attr, iem_w, iem_b, mol_ei, agg_mol, EM);
    gine_msg_kernel<<<EP * 64 / 256, 256, 0, stream>>>(x_prot, prot_edge_attr, iep_w, iep_b, prot_ei, agg_prot, EP);
    gine_mlp_kernel<<<NM / 64, 256, 0, stream>>>(x_mol, agg_mol, gm_w1 + l * 4096, gm_b1 + l * 64,
                                                 gm_w2 + l * 4096, gm_b2 + l * 64, h_mol, NM);
    gine_mlp_kernel<<<NP / 64, 256, 0, stream>>>(x_prot, agg_prot, gp_w1 + l * 4096, gp_b1 + l * 64,
                                                 gp_w2 + l * 4096, gp_b2 + l * 64, h_prot, NP);
    // m2p: Q=mol (m2p W0), K/V=prot (m2p W1,W2); p2m: Q=prot (p2m W0), K/V=mol (p2m W1,W2)
    proj_qkv_kernel<<<NM / 64, 256, 0, stream>>>(h_mol,
        m2p_w + (l * 3 + 0) * 4096, m2p_b + (l * 3 + 0) * 64,
        p2m_w + (l * 3 + 1) * 4096, p2m_b + (l * 3 + 1) * 64,
        p2m_w + (l * 3 + 2) * 4096, p2m_b + (l * 3 + 2) * 64,
        Qm, Km, Vtm, NM);
    proj_qkv_kernel<<<NP / 64, 256, 0, stream>>>(h_prot,
        p2m_w + (l * 3 + 0) * 4096, p2m_b + (l * 3 + 0) * 64,
        m2p_w + (l * 3 + 1) * 4096, m2p_b + (l * 3 + 1) * 64,
        m2p_w + (l * 3 + 2) * 4096, m2p_b + (l * 3 + 2) * 64,
        Qp, Kp, Vtp, NP);
    attn_mfma_kernel<<<dim3(NM / 16, 4), 256, 0, stream>>>(Qm, Kp, Vtp, a_mol, NM, NP);
    attn_mfma_kernel<<<dim3(NP / 16, 4), 256, 0, stream>>>(Qp, Km, Vtm, a_prot, NP, NM);
    ln_add_kernel<<<NM * 64 / 256, 256, 0, stream>>>(h_mol, a_mol, lnm_g + l * 64, lnm_b + l * 64, x_mol, NM);
    ln_add_kernel<<<NP * 64 / 256, 256, 0, stream>>>(h_prot, a_prot, lnp_g + l * 64, lnp_b + l * 64, x_prot, NP);
  }

  (void)hipMemsetAsync(pool, 0, 32 * 128 * 4, stream);
  (void)hipMemsetAsync(cnt, 0, 64 * 4, stream);
  pool_acc_kernel<<<NM * 64 / 256, 256, 0, stream>>>(x_mol, mol_batch, pool, cnt, NM, 0, 0);
  pool_acc_kernel<<<NP * 64 / 256, 256, 0, stream>>>(x_prot, prot_batch, pool, cnt, NP, 64, 32);
  final_kernel<<<1, 256, 0, stream>>>(pool, cnt, fc1_w, fc1_b, fc2_w, fc2_b, (float*)d_out);
}

// Round 5
// 1098.884 us; speedup vs baseline: 1.1097x; 1.1097x over previous
//
#include <hip/hip_runtime.h>
#include <cstddef>

typedef _Float16 f16x4 __attribute__((ext_vector_type(4)));
typedef float f32x4 __attribute__((ext_vector_type(4)));

__device__ __forceinline__ f32x4 mfma16(f16x4 a, f16x4 b, f32x4 c) {
  return __builtin_amdgcn_mfma_f32_16x16x16f16(a, b, c, 0, 0, 0);
}

// Q is pre-scaled by 0.25 * log2(e) so softmax weights are exp2(score).
#define QSCALE (0.25f * 1.44269504f)

// ---------------------------------------------------------------------------
// init node embedding: out[n][o] = b[o] + sum_k in[n][k] * W[k][o]
// ---------------------------------------------------------------------------
__global__ __launch_bounds__(256) void init_embed_kernel(
    const float* __restrict__ in, const float* __restrict__ W,
    const float* __restrict__ b, float* __restrict__ out, int N, int Kin)
{
  int idx = blockIdx.x * 256 + threadIdx.x;
  if (idx >= N * 64) return;
  int n = idx >> 6, o = idx & 63;
  float acc = b[o];
  const float* row = in + (size_t)n * Kin;
  for (int k = 0; k < Kin; k++) acc += row[k] * W[k * 64 + o];
  out[idx] = acc;
}

// ---------------------------------------------------------------------------
// GINE message + aggregate: agg[dst] += relu(x[src] + (attr @ We + be))
// ---------------------------------------------------------------------------
__global__ __launch_bounds__(256) void gine_msg_kernel(
    const float* __restrict__ x, const float* __restrict__ attr,
    const float* __restrict__ We, const float* __restrict__ be,
    const int* __restrict__ ei, float* __restrict__ agg, int E)
{
  int idx = blockIdx.x * 256 + threadIdx.x;
  if (idx >= E * 64) return;
  int e = idx >> 6, d = idx & 63;
  int src = ei[e];
  int dst = ei[E + e];
  float ea = be[d];
  const float* arow = attr + (size_t)e * 10;
  #pragma unroll
  for (int k = 0; k < 10; k++) ea += arow[k] * We[k * 64 + d];
  float m = x[(size_t)src * 64 + d] + ea;
  m = fmaxf(m, 0.f);
  atomicAdd(&agg[(size_t)dst * 64 + d], m);
}

// ---------------------------------------------------------------------------
// GINE node MLP, fused: out = relu( relu((x+agg)@W1 + B1) @ W2 + B2 )
// ---------------------------------------------------------------------------
__global__ __launch_bounds__(256) void gine_mlp_kernel(
    const float* __restrict__ x, const float* __restrict__ agg,
    const float* __restrict__ W1, const float* __restrict__ B1,
    const float* __restrict__ W2, const float* __restrict__ B2,
    float* __restrict__ out, int N)
{
  __shared__ __align__(16) float sW1[64 * 64];
  __shared__ __align__(16) float sW2[64 * 64];
  __shared__ __align__(16) float sBuf[64 * 68];
  int t = threadIdx.x;
  int n0 = blockIdx.x * 64;
  #pragma unroll
  for (int i = 0; i < 16; i++) { int f = t + i * 256; sW1[f] = W1[f]; sW2[f] = W2[f]; }
  #pragma unroll
  for (int i = 0; i < 16; i++) {
    int f = t + i * 256;
    size_t g = (size_t)n0 * 64 + f;
    sBuf[(f >> 6) * 68 + (f & 63)] = x[g] + agg[g];
  }
  __syncthreads();
  int n = t >> 2, kk = t & 3;
  float acc[16];
  #pragma unroll
  for (int j = 0; j < 16; j++) acc[j] = B1[kk * 16 + j];
  #pragma unroll
  for (int d = 0; d < 64; d++) {
    float xv = sBuf[n * 68 + d];
    const float* wrow = &sW1[d * 64 + kk * 16];
    #pragma unroll
    for (int j = 0; j < 16; j++) acc[j] += xv * wrow[j];
  }
  __syncthreads();
  #pragma unroll
  for (int j = 0; j < 16; j++) sBuf[n * 68 + kk * 16 + j] = fmaxf(acc[j], 0.f);
  __syncthreads();
  #pragma unroll
  for (int j = 0; j < 16; j++) acc[j] = B2[kk * 16 + j];
  #pragma unroll
  for (int d = 0; d < 64; d++) {
    float xv = sBuf[n * 68 + d];
    const float* wrow = &sW2[d * 64 + kk * 16];
    #pragma unroll
    for (int j = 0; j < 16; j++) acc[j] += xv * wrow[j];
  }
  float* op = out + (size_t)(n0 + n) * 64 + kk * 16;
  #pragma unroll
  for (int j = 0; j < 16; j++) op[j] = fmaxf(acc[j], 0.f);
}

// ---------------------------------------------------------------------------
// Fused QKV projection. Q,K -> fp16 head-major [h][n][16] (Q scaled);
// V -> fp16 transposed [h][16][N].
// ---------------------------------------------------------------------------
__global__ __launch_bounds__(256) void proj_qkv_kernel(
    const float* __restrict__ xin,
    const float* __restrict__ Wq, const float* __restrict__ bq,
    const float* __restrict__ Wk, const float* __restrict__ bk,
    const float* __restrict__ Wv, const float* __restrict__ bv,
    _Float16* __restrict__ Qo, _Float16* __restrict__ Ko,
    _Float16* __restrict__ Vto, int N)
{
  __shared__ __align__(16) float sW[64 * 64];
  __shared__ __align__(16) float sIn[64 * 68];
  int t = threadIdx.x;
  int n0 = blockIdx.x * 64;
  #pragma unroll
  for (int i = 0; i < 16; i++) {
    int f = t + i * 256;
    sIn[(f >> 6) * 68 + (f & 63)] = xin[(size_t)n0 * 64 + f];
  }
  int n = t >> 2, kk = t & 3;
  const float* Ws[3] = {Wq, Wk, Wv};
  const float* bs[3] = {bq, bk, bv};
  for (int p = 0; p < 3; p++) {
    __syncthreads();
    #pragma unroll
    for (int i = 0; i < 16; i++) { int f = t + i * 256; sW[f] = Ws[p][f]; }
    __syncthreads();
    float acc[16];
    #pragma unroll
    for (int j = 0; j < 16; j++) acc[j] = bs[p][kk * 16 + j];
    #pragma unroll
    for (int d = 0; d < 64; d++) {
      float xv = sIn[n * 68 + d];
      const float* wrow = &sW[d * 64 + kk * 16];
      #pragma unroll
      for (int j = 0; j < 16; j++) acc[j] += xv * wrow[j];
    }
    if (p == 2) {
      #pragma unroll
      for (int j = 0; j < 16; j++)
        Vto[((size_t)kk * 16 + j) * N + (n0 + n)] = (_Float16)acc[j];
    } else {
      float scale = (p == 0) ? QSCALE : 1.0f;
      _Float16 tmp[16];
      #pragma unroll
      for (int j = 0; j < 16; j++) tmp[j] = (_Float16)(acc[j] * scale);
      _Float16* base = (p == 0) ? Qo : Ko;
      float4* dst = (float4*)(base + ((size_t)kk * N + n0 + n) * 16);
      dst[0] = ((float4*)tmp)[0];
      dst[1] = ((float4*)tmp)[1];
    }
  }
}

// ---------------------------------------------------------------------------
// MFMA flash cross-attention, no-max softmax, 64 queries per block.
// Q,K: fp16 [H][N][16]; Vt: fp16 [H][16][N]; out: fp32 [Nq][64].
// Block = 64 queries x 1 head, 4 waves; wave w owns key chunks w*64+256*i
// (K/V read ONCE per block, split across waves). Each wave holds 4 Q-frags
// (q-chunks of 16) and 4 O-accumulators: 32 MFMA per 64-key tile on the
// same 8 global loads -> 4x less L2 traffic than 16q/block.
// Scores computed transposed (D[key][q]) so exp2(D) feeds the PV MFMA's
// B operand directly. LDS only in the final cross-wave combine.
// ---------------------------------------------------------------------------
__global__ __launch_bounds__(256) void attn_mfma_kernel(
    const _Float16* __restrict__ Q, const _Float16* __restrict__ K,
    const _Float16* __restrict__ Vt, float* __restrict__ out, int Nq, int Nk)
{
  const int h = blockIdx.y;
  const int q0 = blockIdx.x * 64;
  const int t = threadIdx.x;
  const int wave = t >> 6, lane = t & 63;
  const int l16 = lane & 15, quad = lane >> 4;

  // Q B-frags: B[k=d=quad*4+i][n=q=g*16+l16]
  f16x4 qf[4];
  #pragma unroll
  for (int g = 0; g < 4; g++)
    qf[g] = *(const f16x4*)(Q + ((size_t)h * Nq + q0 + g * 16 + l16) * 16 + quad * 4);
  const _Float16* Kh = K + (size_t)h * Nk * 16;
  const _Float16* Vh = Vt + ((size_t)h * 16 + l16) * Nk;

  f32x4 oacc[4] = {{0.f,0.f,0.f,0.f},{0.f,0.f,0.f,0.f},{0.f,0.f,0.f,0.f},{0.f,0.f,0.f,0.f}};
  float lacc[4] = {0.f, 0.f, 0.f, 0.f};
  const f32x4 zero = {0.f, 0.f, 0.f, 0.f};

  for (int kb = wave * 64; kb < Nk; kb += 256) {
    f16x4 kf[4], vf[4];
    #pragma unroll
    for (int c = 0; c < 4; c++) {
      // K A-frag: A[m=key=l16][k=d=quad*4+i]
      kf[c] = *(const f16x4*)(Kh + (size_t)(kb + c * 16 + l16) * 16 + quad * 4);
      // V^T A-frag: A[m=d=l16][k=key=quad*4+i]
      vf[c] = *(const f16x4*)(Vh + kb + c * 16 + quad * 4);
    }
    #pragma unroll
    for (int g = 0; g < 4; g++) {
      f32x4 s[4];
      #pragma unroll
      for (int c = 0; c < 4; c++) s[c] = mfma16(kf[c], qf[g], zero);
      f16x4 pf[4];
      #pragma unroll
      for (int c = 0; c < 4; c++)
        #pragma unroll
        for (int r = 0; r < 4; r++) {
          float p = exp2f(fminf(s[c][r], 14.f));
          lacc[g] += p;
          pf[c][r] = (_Float16)p;
        }
      #pragma unroll
      for (int c = 0; c < 4; c++) oacc[g] = mfma16(vf[c], pf[c], oacc[g]);
    }
  }

  // cross-wave combine, per q-chunk
  __shared__ float sO[4][4][16][16];   // [chunk][wave][d][q]
  __shared__ float sl[4][4][4][16];    // [chunk][wave][quad][q]
  #pragma unroll
  for (int g = 0; g < 4; g++) {
    #pragma unroll
    for (int r = 0; r < 4; r++) sO[g][wave][quad * 4 + r][l16] = oacc[g][r];
    sl[g][wave][quad][l16] = lacc[g];
  }
  __syncthreads();
  {
    int q = t >> 4, d = t & 15;
    #pragma unroll
    for (int g = 0; g < 4; g++) {
      float O = 0.f, L = 0.f;
      #pragma unroll
      for (int w = 0; w < 4; w++) {
        O += sO[g][w][d][q];
        #pragma unroll
        for (int qd = 0; qd < 4; qd++) L += sl[g][w][qd][q];
      }
      out[(size_t)(q0 + g * 16 + q) * 64 + h * 16 + d] = O / L;
    }
  }
}

// ---------------------------------------------------------------------------
// LayerNorm(h + a) * g + b
// ---------------------------------------------------------------------------
__global__ __launch_bounds__(256) void ln_add_kernel(
    const float* __restrict__ h, const float* __restrict__ a,
    const float* __restrict__ g, const float* __restrict__ bb,
    float* __restrict__ out, int N)
{
  int idx = blockIdx.x * 256 + threadIdx.x;
  if (idx >= N * 64) return;
  int d = idx & 63;
  float v = h[idx] + a[idx];
  float sm = v;
  #pragma unroll
  for (int o = 1; o < 64; o <<= 1) sm += __shfl_xor(sm, o);
  float mu = sm * 0.015625f;
  float c = v - mu;
  float q = c * c;
  #pragma unroll
  for (int o = 1; o < 64; o <<= 1) q += __shfl_xor(q, o);
  float var = q * 0.015625f;
  out[idx] = c * rsqrtf(var + 1e-5f) * g[d] + bb[d];
}

// ---------------------------------------------------------------------------
// segment-sum pooling
// ---------------------------------------------------------------------------
__global__ __launch_bounds__(256) void pool_acc_kernel(
    const float* __restrict__ x, const int* __restrict__ batch,
    float* __restrict__ sums, float* __restrict__ cnt, int N, int colOff, int cntOff)
{
  int idx = blockIdx.x * 256 + threadIdx.x;
  if (idx >= N * 64) return;
  int n = idx >> 6, d = idx & 63;
  int seg = batch[n];
  atomicAdd(&sums[seg * 128 + colOff + d], x[idx]);
  if (d == 0) atomicAdd(&cnt[cntOff + seg], 1.0f);
}

// ---------------------------------------------------------------------------
// final head
// ---------------------------------------------------------------------------
__global__ __launch_bounds__(256) void final_kernel(
    const float* __restrict__ sums, const float* __restrict__ cnt,
    const float* __restrict__ fc1w, const float* __restrict__ fc1b,
    const float* __restrict__ fc2w, const float* __restrict__ fc2b,
    float* __restrict__ out)
{
  __shared__ float z[32 * 128];
  __shared__ float h1[32 * 64];
  int t = threadIdx.x;
  for (int f = t; f < 32 * 128; f += 256) {
    int s = f >> 7, j = f & 127;
    float c = cnt[(j >> 6) * 32 + s];
    z[f] = sums[f] / fmaxf(c, 1.f);
  }
  __syncthreads();
  for (int f = t; f < 32 * 64; f += 256) {
    int s = f >> 6, o = f & 63;
    float acc = fc1b[o];
    for (int j = 0; j < 128; j++) acc += z[s * 128 + j] * fc1w[j * 64 + o];
    h1[f] = fmaxf(acc, 0.f);
  }
  __syncthreads();
  if (t < 32) {
    float acc = fc2b[0];
    for (int o = 0; o < 64; o++) acc += h1[t * 64 + o] * fc2w[o];
    out[t] = 1.f / (1.f + __expf(-acc));
  }
}

// ---------------------------------------------------------------------------
extern "C" void kernel_launch(void* const* d_in, const int* in_sizes, int n_in,
                              void* d_out, int out_size, void* d_ws, size_t ws_size,
                              hipStream_t stream)
{
  (void)in_sizes; (void)n_in; (void)out_size; (void)ws_size;
  const float* mol_x          = (const float*)d_in[0];
  const float* prot_x         = (const float*)d_in[1];
  const float* mol_edge_attr  = (const float*)d_in[2];
  const float* prot_edge_attr = (const float*)d_in[3];
  const float* inm_w = (const float*)d_in[4];
  const float* inm_b = (const float*)d_in[5];
  const float* inp_w = (const float*)d_in[6];
  const float* inp_b = (const float*)d_in[7];
  const float* iem_w = (const float*)d_in[8];
  const float* iem_b = (const float*)d_in[9];
  const float* iep_w = (const float*)d_in[10];
  const float* iep_b = (const float*)d_in[11];
  const float* gm_w1 = (const float*)d_in[12];
  const float* gm_b1 = (const float*)d_in[13];
  const float* gm_w2 = (const float*)d_in[14];
  const float* gm_b2 = (const float*)d_in[15];
  const float* gp_w1 = (const float*)d_in[16];
  const float* gp_b1 = (const float*)d_in[17];
  const float* gp_w2 = (const float*)d_in[18];
  const float* gp_b2 = (const float*)d_in[19];
  const float* m2p_w = (const float*)d_in[20];
  const float* m2p_b = (const float*)d_in[21];
  const float* p2m_w = (const float*)d_in[22];
  const float* p2m_b = (const float*)d_in[23];
  const float* lnm_g = (const float*)d_in[24];
  const float* lnm_b = (const float*)d_in[25];
  const float* lnp_g = (const float*)d_in[26];
  const float* lnp_b = (const float*)d_in[27];
  const float* fc1_w = (const float*)d_in[28];
  const float* fc1_b = (const float*)d_in[29];
  const float* fc2_w = (const float*)d_in[30];
  const float* fc2_b = (const float*)d_in[31];
  const int* mol_ei     = (const int*)d_in[32];
  const int* prot_ei    = (const int*)d_in[33];
  const int* mol_batch  = (const int*)d_in[34];
  const int* prot_batch = (const int*)d_in[35];

  const int NM = 4096, NP = 8192, EM = 65536, EP = 262144;

  float* ws = (float*)d_ws;
  size_t off = 0;
  auto nxt  = [&](size_t n) { float* p = ws + off; off += n; return p; };
  auto nxtH = [&](size_t n) { _Float16* p = (_Float16*)(ws + off); off += (n + 1) / 2; return p; };
  float* x_mol    = nxt((size_t)NM * 64);
  float* x_prot   = nxt((size_t)NP * 64);
  float* agg_mol  = nxt((size_t)NM * 64);
  float* agg_prot = nxt((size_t)NP * 64);
  float* h_mol    = nxt((size_t)NM * 64);
  float* h_prot   = nxt((size_t)NP * 64);
  float* a_mol    = nxt((size_t)NM * 64);
  float* a_prot   = nxt((size_t)NP * 64);
  _Float16* Qm  = nxtH((size_t)NM * 64);
  _Float16* Km  = nxtH((size_t)NM * 64);
  _Float16* Vtm = nxtH((size_t)NM * 64);
  _Float16* Qp  = nxtH((size_t)NP * 64);
  _Float16* Kp  = nxtH((size_t)NP * 64);
  _Float16* Vtp = nxtH((size_t)NP * 64);
  float* pool = nxt(32 * 128);
  float* cnt  = nxt(64);

  init_embed_kernel<<<NM * 64 / 256, 256, 0, stream>>>(mol_x, inm_w, inm_b, x_mol, NM, 11);
  init_embed_kernel<<<NP * 64 / 256, 256, 0, stream>>>(prot_x, inp_w, inp_b, x_prot, NP, 15);

  for (int l = 0; l < 3; l++) {
    (void)hipMemsetAsync(agg_mol, 0, (size_t)NM * 64 * 4, stream);
    (void)hipMemsetAsync(agg_prot, 0, (size_t)NP * 64 * 4, stream);
    gine_msg_kernel<<<EM * 64 / 256, 256, 0, stream>>>(x_mol, mol_edge_attr, iem_w, iem_b, mol_ei, agg_mol, EM);
    gine_msg_kernel<<<EP * 64 / 256, 256, 0, stream>>>(x_prot, prot_edge_attr, iep_w, iep_b, prot_ei, agg_prot, EP);
    gine_mlp_kernel<<<NM / 64, 256, 0, stream>>>(x_mol, agg_mol, gm_w1 + l * 4096, gm_b1 + l * 64,
                                                 gm_w2 + l * 4096, gm_b2 + l * 64, h_mol, NM);
    gine_mlp_kernel<<<NP / 64, 256, 0, stream>>>(x_prot, agg_prot, gp_w1 + l * 4096, gp_b1 + l * 64,
                                                 gp_w2 + l * 4096, gp_b2 + l * 64, h_prot, NP);
    // m2p: Q=mol (m2p W0), K/V=prot (m2p W1,W2); p2m: Q=prot (p2m W0), K/V=mol (p2m W1,W2)
    proj_qkv_kernel<<<NM / 64, 256, 0, stream>>>(h_mol,
        m2p_w + (l * 3 + 0) * 4096, m2p_b + (l * 3 + 0) * 64,
        p2m_w + (l * 3 + 1) * 4096, p2m_b + (l * 3 + 1) * 64,
        p2m_w + (l * 3 + 2) * 4096, p2m_b + (l * 3 + 2) * 64,
        Qm, Km, Vtm, NM);
    proj_qkv_kernel<<<NP / 64, 256, 0, stream>>>(h_prot,
        p2m_w + (l * 3 + 0) * 4096, p2m_b + (l * 3 + 0) * 64,
        m2p_w + (l * 3 + 1) * 4096, m2p_b + (l * 3 + 1) * 64,
        m2p_w + (l * 3 + 2) * 4096, m2p_b + (l * 3 + 2) * 64,
        Qp, Kp, Vtp, NP);
    attn_mfma_kernel<<<dim3(NM / 64, 4), 256, 0, stream>>>(Qm, Kp, Vtp, a_mol, NM, NP);
    attn_mfma_kernel<<<dim3(NP / 64, 4), 256, 0, stream>>>(Qp, Km, Vtm, a_prot, NP, NM);
    ln_add_kernel<<<NM * 64 / 256, 256, 0, stream>>>(h_mol, a_mol, lnm_g + l * 64, lnm_b + l * 64, x_mol, NM);
    ln_add_kernel<<<NP * 64 / 256, 256, 0, stream>>>(h_prot, a_prot, lnp_g + l * 64, lnp_b + l * 64, x_prot, NP);
  }

  (void)hipMemsetAsync(pool, 0, 32 * 128 * 4, stream);
  (void)hipMemsetAsync(cnt, 0, 64 * 4, stream);
  pool_acc_kernel<<<NM * 64 / 256, 256, 0, stream>>>(x_mol, mol_batch, pool, cnt, NM, 0, 0);
  pool_acc_kernel<<<NP * 64 / 256, 256, 0, stream>>>(x_prot, prot_batch, pool, cnt, NP, 64, 32);
  final_kernel<<<1, 256, 0, stream>>>(pool, cnt, fc1_w, fc1_b, fc2_w, fc2_b, (float*)d_out);
}

// Round 6
// 829.885 us; speedup vs baseline: 1.4693x; 1.3241x over previous
//
#include <hip/hip_runtime.h>
#include <cstddef>

typedef _Float16 f16x4 __attribute__((ext_vector_type(4)));
typedef float f32x4 __attribute__((ext_vector_type(4)));

__device__ __forceinline__ f32x4 mfma16(f16x4 a, f16x4 b, f32x4 c) {
  return __builtin_amdgcn_mfma_f32_16x16x16f16(a, b, c, 0, 0, 0);
}

// Q is pre-scaled by 0.25 * log2(e) so softmax weights are exp2(score).
#define QSCALE (0.25f * 1.44269504f)
#define NSPLIT 8

// ---------------------------------------------------------------------------
// init node embedding: out[n][o] = b[o] + sum_k in[n][k] * W[k][o]
// ---------------------------------------------------------------------------
__global__ __launch_bounds__(256) void init_embed_kernel(
    const float* __restrict__ in, const float* __restrict__ W,
    const float* __restrict__ b, float* __restrict__ out, int N, int Kin)
{
  int idx = blockIdx.x * 256 + threadIdx.x;
  if (idx >= N * 64) return;
  int n = idx >> 6, o = idx & 63;
  float acc = b[o];
  const float* row = in + (size_t)n * Kin;
  for (int k = 0; k < Kin; k++) acc += row[k] * W[k * 64 + o];
  out[idx] = acc;
}

// ---------------------------------------------------------------------------
// GINE message + aggregate for BOTH graphs in one launch.
// agg[dst] += relu(x[src] + (attr @ We + be)); one wave per edge.
// Block ranges: [0, EM*64/256) mol, rest prot (EM*64 divisible by 256).
// ---------------------------------------------------------------------------
__global__ __launch_bounds__(256) void gine_msg_dual(
    const float* __restrict__ xm, const float* __restrict__ attrm,
    const float* __restrict__ Wem, const float* __restrict__ bem,
    const int* __restrict__ eim, float* __restrict__ aggm, int EM,
    const float* __restrict__ xp, const float* __restrict__ attrp,
    const float* __restrict__ Wep, const float* __restrict__ bep,
    const int* __restrict__ eip, float* __restrict__ aggp, int EP)
{
  int idx = blockIdx.x * 256 + threadIdx.x;
  const float *x, *attr, *We, *be;
  const int* ei;
  float* agg;
  int E, li;
  int totalM = EM * 64;
  if (idx < totalM) {
    x = xm; attr = attrm; We = Wem; be = bem; ei = eim; agg = aggm; E = EM; li = idx;
  } else {
    li = idx - totalM;
    if (li >= EP * 64) return;
    x = xp; attr = attrp; We = Wep; be = bep; ei = eip; agg = aggp; E = EP;
  }
  int e = li >> 6, d = li & 63;
  int src = ei[e];
  int dst = ei[E + e];
  float ea = be[d];
  const float* arow = attr + (size_t)e * 10;
  #pragma unroll
  for (int k = 0; k < 10; k++) ea += arow[k] * We[k * 64 + d];
  float m = x[(size_t)src * 64 + d] + ea;
  m = fmaxf(m, 0.f);
  atomicAdd(&agg[(size_t)dst * 64 + d], m);
}

// ---------------------------------------------------------------------------
// GINE node MLP for BOTH graphs: out = relu(relu((x+agg)@W1+B1)@W2+B2)
// blocks [0,64) mol, [64,192) prot.
// ---------------------------------------------------------------------------
__global__ __launch_bounds__(256) void gine_mlp_dual(
    const float* __restrict__ xm, const float* __restrict__ aggm,
    const float* __restrict__ W1m, const float* __restrict__ B1m,
    const float* __restrict__ W2m, const float* __restrict__ B2m,
    float* __restrict__ outm,
    const float* __restrict__ xp, const float* __restrict__ aggp,
    const float* __restrict__ W1p, const float* __restrict__ B1p,
    const float* __restrict__ W2p, const float* __restrict__ B2p,
    float* __restrict__ outp)
{
  __shared__ __align__(16) float sW1[64 * 64];
  __shared__ __align__(16) float sW2[64 * 64];
  __shared__ __align__(16) float sBuf[64 * 68];
  int t = threadIdx.x;
  int b = blockIdx.x;
  const float *x, *agg, *W1, *B1, *W2, *B2;
  float* out;
  int n0;
  if (b < 64) {
    x = xm; agg = aggm; W1 = W1m; B1 = B1m; W2 = W2m; B2 = B2m; out = outm; n0 = b * 64;
  } else {
    x = xp; agg = aggp; W1 = W1p; B1 = B1p; W2 = W2p; B2 = B2p; out = outp; n0 = (b - 64) * 64;
  }
  #pragma unroll
  for (int i = 0; i < 16; i++) { int f = t + i * 256; sW1[f] = W1[f]; sW2[f] = W2[f]; }
  #pragma unroll
  for (int i = 0; i < 16; i++) {
    int f = t + i * 256;
    size_t g = (size_t)n0 * 64 + f;
    sBuf[(f >> 6) * 68 + (f & 63)] = x[g] + agg[g];
  }
  __syncthreads();
  int n = t >> 2, kk = t & 3;
  float acc[16];
  #pragma unroll
  for (int j = 0; j < 16; j++) acc[j] = B1[kk * 16 + j];
  #pragma unroll
  for (int d = 0; d < 64; d++) {
    float xv = sBuf[n * 68 + d];
    const float* wrow = &sW1[d * 64 + kk * 16];
    #pragma unroll
    for (int j = 0; j < 16; j++) acc[j] += xv * wrow[j];
  }
  __syncthreads();
  #pragma unroll
  for (int j = 0; j < 16; j++) sBuf[n * 68 + kk * 16 + j] = fmaxf(acc[j], 0.f);
  __syncthreads();
  #pragma unroll
  for (int j = 0; j < 16; j++) acc[j] = B2[kk * 16 + j];
  #pragma unroll
  for (int d = 0; d < 64; d++) {
    float xv = sBuf[n * 68 + d];
    const float* wrow = &sW2[d * 64 + kk * 16];
    #pragma unroll
    for (int j = 0; j < 16; j++) acc[j] += xv * wrow[j];
  }
  float* op = out + (size_t)(n0 + n) * 64 + kk * 16;
  #pragma unroll
  for (int j = 0; j < 16; j++) op[j] = fmaxf(acc[j], 0.f);
}

// ---------------------------------------------------------------------------
// Fused QKV projection for BOTH graphs. Q,K -> fp16 [h][n][16] (Q scaled);
// V -> fp16 transposed [h][16][N]. blocks [0,64) mol, [64,192) prot.
// ---------------------------------------------------------------------------
__global__ __launch_bounds__(256) void proj_qkv_dual(
    const float* __restrict__ xm,
    const float* __restrict__ Wqm, const float* __restrict__ bqm,
    const float* __restrict__ Wkm, const float* __restrict__ bkm,
    const float* __restrict__ Wvm, const float* __restrict__ bvm,
    _Float16* __restrict__ Qom, _Float16* __restrict__ Kom, _Float16* __restrict__ Vtom,
    const float* __restrict__ xp,
    const float* __restrict__ Wqp, const float* __restrict__ bqp,
    const float* __restrict__ Wkp, const float* __restrict__ bkp,
    const float* __restrict__ Wvp, const float* __restrict__ bvp,
    _Float16* __restrict__ Qop, _Float16* __restrict__ Kop, _Float16* __restrict__ Vtop)
{
  __shared__ __align__(16) float sW[64 * 64];
  __shared__ __align__(16) float sIn[64 * 68];
  int t = threadIdx.x;
  int b = blockIdx.x;
  const float *xin, *Wq, *bq, *Wk, *bk, *Wv, *bv;
  _Float16 *Qo, *Ko, *Vto;
  int n0, N;
  if (b < 64) {
    xin = xm; Wq = Wqm; bq = bqm; Wk = Wkm; bk = bkm; Wv = Wvm; bv = bvm;
    Qo = Qom; Ko = Kom; Vto = Vtom; n0 = b * 64; N = 4096;
  } else {
    xin = xp; Wq = Wqp; bq = bqp; Wk = Wkp; bk = bkp; Wv = Wvp; bv = bvp;
    Qo = Qop; Ko = Kop; Vto = Vtop; n0 = (b - 64) * 64; N = 8192;
  }
  #pragma unroll
  for (int i = 0; i < 16; i++) {
    int f = t + i * 256;
    sIn[(f >> 6) * 68 + (f & 63)] = xin[(size_t)n0 * 64 + f];
  }
  int n = t >> 2, kk = t & 3;
  const float* Ws[3] = {Wq, Wk, Wv};
  const float* bs[3] = {bq, bk, bv};
  for (int p = 0; p < 3; p++) {
    __syncthreads();
    #pragma unroll
    for (int i = 0; i < 16; i++) { int f = t + i * 256; sW[f] = Ws[p][f]; }
    __syncthreads();
    float acc[16];
    #pragma unroll
    for (int j = 0; j < 16; j++) acc[j] = bs[p][kk * 16 + j];
    #pragma unroll
    for (int d = 0; d < 64; d++) {
      float xv = sIn[n * 68 + d];
      const float* wrow = &sW[d * 64 + kk * 16];
      #pragma unroll
      for (int j = 0; j < 16; j++) acc[j] += xv * wrow[j];
    }
    if (p == 2) {
      #pragma unroll
      for (int j = 0; j < 16; j++)
        Vto[((size_t)kk * 16 + j) * N + (n0 + n)] = (_Float16)acc[j];
    } else {
      float scale = (p == 0) ? QSCALE : 1.0f;
      _Float16 tmp[16];
      #pragma unroll
      for (int j = 0; j < 16; j++) tmp[j] = (_Float16)(acc[j] * scale);
      _Float16* base = (p == 0) ? Qo : Ko;
      float4* dst = (float4*)(base + ((size_t)kk * N + n0 + n) * 16);
      dst[0] = ((float4*)tmp)[0];
      dst[1] = ((float4*)tmp)[1];
    }
  }
}

// ---------------------------------------------------------------------------
// Key-split MFMA cross-attention, no-max softmax. Grid (Nq/64, H, NSPLIT).
// Each block: 64 queries x 1 head x Nk/NSPLIT keys; 4 waves own disjoint
// 64-key chunks. Writes UNNORMALIZED partial O and partial L to workspace;
// the division happens in ln_combine_dual (pure sum across splits since
// weights are absolute exp2, no per-split max).
// ---------------------------------------------------------------------------
__global__ __launch_bounds__(256) void attn_split_kernel(
    const _Float16* __restrict__ Q, const _Float16* __restrict__ K,
    const _Float16* __restrict__ Vt, float* __restrict__ Opart,
    float* __restrict__ Lpart, int Nq, int Nk)
{
  const int h = blockIdx.y;
  const int q0 = blockIdx.x * 64;
  const int split = blockIdx.z;
  const int Ks = Nk / NSPLIT;
  const int t = threadIdx.x;
  const int wave = t >> 6, lane = t & 63;
  const int l16 = lane & 15, quad = lane >> 4;

  f16x4 qf[4];
  #pragma unroll
  for (int g = 0; g < 4; g++)
    qf[g] = *(const f16x4*)(Q + ((size_t)h * Nq + q0 + g * 16 + l16) * 16 + quad * 4);
  const _Float16* Kh = K + (size_t)h * Nk * 16;
  const _Float16* Vh = Vt + ((size_t)h * 16 + l16) * Nk;

  f32x4 oacc[4] = {{0.f,0.f,0.f,0.f},{0.f,0.f,0.f,0.f},{0.f,0.f,0.f,0.f},{0.f,0.f,0.f,0.f}};
  float lacc[4] = {0.f, 0.f, 0.f, 0.f};
  const f32x4 zero = {0.f, 0.f, 0.f, 0.f};

  const int kend = (split + 1) * Ks;
  for (int kb = split * Ks + wave * 64; kb < kend; kb += 256) {
    f16x4 kf[4], vf[4];
    #pragma unroll
    for (int c = 0; c < 4; c++) {
      kf[c] = *(const f16x4*)(Kh + (size_t)(kb + c * 16 + l16) * 16 + quad * 4);
      vf[c] = *(const f16x4*)(Vh + kb + c * 16 + quad * 4);
    }
    #pragma unroll
    for (int g = 0; g < 4; g++) {
      f32x4 s[4];
      #pragma unroll
      for (int c = 0; c < 4; c++) s[c] = mfma16(kf[c], qf[g], zero);
      f16x4 pf[4];
      #pragma unroll
      for (int c = 0; c < 4; c++)
        #pragma unroll
        for (int r = 0; r < 4; r++) {
          float p = exp2f(fminf(s[c][r], 14.f));
          lacc[g] += p;
          pf[c][r] = (_Float16)p;
        }
      #pragma unroll
      for (int c = 0; c < 4; c++) oacc[g] = mfma16(vf[c], pf[c], oacc[g]);
    }
  }

  // cross-wave combine, per q-chunk; store partials (no divide)
  __shared__ float sO[4][4][16][16];   // [chunk][wave][d][q]
  __shared__ float sl[4][4][4][16];    // [chunk][wave][quad][q]
  #pragma unroll
  for (int g = 0; g < 4; g++) {
    #pragma unroll
    for (int r = 0; r < 4; r++) sO[g][wave][quad * 4 + r][l16] = oacc[g][r];
    sl[g][wave][quad][l16] = lacc[g];
  }
  __syncthreads();
  {
    int q = t >> 4, d = t & 15;
    #pragma unroll
    for (int g = 0; g < 4; g++) {
      float O = 0.f, L = 0.f;
      #pragma unroll
      for (int w = 0; w < 4; w++) {
        O += sO[g][w][d][q];
        #pragma unroll
        for (int qd = 0; qd < 4; qd++) L += sl[g][w][qd][q];
      }
      size_t row = (size_t)split * Nq + q0 + g * 16 + q;
      Opart[row * 64 + h * 16 + d] = O;
      if (d == 0) Lpart[row * 4 + h] = L;
    }
  }
}

// ---------------------------------------------------------------------------
// Fused attn-split combine + LayerNorm(h + O/L) * g + b, BOTH graphs.
// blocks [0, NM*64/256) mol, rest prot.
// ---------------------------------------------------------------------------
__global__ __launch_bounds__(256) void ln_combine_dual(
    const float* __restrict__ hm, const float* __restrict__ Om,
    const float* __restrict__ Lm, const float* __restrict__ gm,
    const float* __restrict__ bm, float* __restrict__ outm, int NM,
    const float* __restrict__ hp, const float* __restrict__ Op,
    const float* __restrict__ Lp, const float* __restrict__ gp,
    const float* __restrict__ bp, float* __restrict__ outp, int NP)
{
  int idx = blockIdx.x * 256 + threadIdx.x;
  const float *hb, *Opart, *Lpart, *g, *bb;
  float* out;
  int N;
  int totalM = NM * 64;
  if (idx < totalM) {
    hb = hm; Opart = Om; Lpart = Lm; g = gm; bb = bm; out = outm; N = NM;
  } else {
    idx -= totalM;
    if (idx >= NP * 64) return;
    hb = hp; Opart = Op; Lpart = Lp; g = gp; bb = bp; out = outp; N = NP;
  }
  int n = idx >> 6, d = idx & 63, h = d >> 4;
  float O = 0.f, L = 0.f;
  #pragma unroll
  for (int s = 0; s < NSPLIT; s++) {
    size_t row = (size_t)s * N + n;
    O += Opart[row * 64 + d];
    L += Lpart[row * 4 + h];
  }
  float v = hb[idx] + O / L;
  float sm = v;
  #pragma unroll
  for (int o = 1; o < 64; o <<= 1) sm += __shfl_xor(sm, o);
  float mu = sm * 0.015625f;
  float c = v - mu;
  float q = c * c;
  #pragma unroll
  for (int o = 1; o < 64; o <<= 1) q += __shfl_xor(q, o);
  float var = q * 0.015625f;
  out[idx] = c * rsqrtf(var + 1e-5f) * g[d] + bb[d];
}

// ---------------------------------------------------------------------------
// Pooling via sorted-run register accumulation: one wave per 64-node chunk,
// lane = dim. batch is sorted -> ~1-2 atomic flushes per chunk instead of 64.
// waves [0,64) mol, [64,192) prot.
// ---------------------------------------------------------------------------
__global__ __launch_bounds__(256) void pool_run_kernel(
    const float* __restrict__ xm, const int* __restrict__ bm,
    const float* __restrict__ xp, const int* __restrict__ bp,
    float* __restrict__ sums, float* __restrict__ cnt)
{
  int wid = (blockIdx.x * 256 + threadIdx.x) >> 6;
  int lane = threadIdx.x & 63;
  const float* x;
  const int* batch;
  int n0, colOff, cntOff;
  if (wid < 64) {
    x = xm; batch = bm; n0 = wid * 64; colOff = 0; cntOff = 0;
  } else {
    wid -= 64;
    if (wid >= 128) return;
    x = xp; batch = bp; n0 = wid * 64; colOff = 64; cntOff = 32;
  }
  float acc = 0.f;
  int cur = batch[n0];
  int run = 0;
  for (int i = 0; i < 64; i++) {
    int n = n0 + i;
    int s = batch[n];
    if (s != cur) {
      atomicAdd(&sums[cur * 128 + colOff + lane], acc);
      if (lane == 0) atomicAdd(&cnt[cntOff + cur], (float)run);
      acc = 0.f; run = 0; cur = s;
    }
    acc += x[(size_t)n * 64 + lane];
    run++;
  }
  atomicAdd(&sums[cur * 128 + colOff + lane], acc);
  if (lane == 0) atomicAdd(&cnt[cntOff + cur], (float)run);
}

// ---------------------------------------------------------------------------
// final head
// ---------------------------------------------------------------------------
__global__ __launch_bounds__(256) void final_kernel(
    const float* __restrict__ sums, const float* __restrict__ cnt,
    const float* __restrict__ fc1w, const float* __restrict__ fc1b,
    const float* __restrict__ fc2w, const float* __restrict__ fc2b,
    float* __restrict__ out)
{
  __shared__ float z[32 * 128];
  __shared__ float h1[32 * 64];
  int t = threadIdx.x;
  for (int f = t; f < 32 * 128; f += 256) {
    int s = f >> 7, j = f & 127;
    float c = cnt[(j >> 6) * 32 + s];
    z[f] = sums[f] / fmaxf(c, 1.f);
  }
  __syncthreads();
  for (int f = t; f < 32 * 64; f += 256) {
    int s = f >> 6, o = f & 63;
    float acc = fc1b[o];
    for (int j = 0; j < 128; j++) acc += z[s * 128 + j] * fc1w[j * 64 + o];
    h1[f] = fmaxf(acc, 0.f);
  }
  __syncthreads();
  if (t < 32) {
    float acc = fc2b[0];
    for (int o = 0; o < 64; o++) acc += h1[t * 64 + o] * fc2w[o];
    out[t] = 1.f / (1.f + __expf(-acc));
  }
}

// ---------------------------------------------------------------------------
extern "C" void kernel_launch(void* const* d_in, const int* in_sizes, int n_in,
                              void* d_out, int out_size, void* d_ws, size_t ws_size,
                              hipStream_t stream)
{
  (void)in_sizes; (void)n_in; (void)out_size; (void)ws_size;
  const float* mol_x          = (const float*)d_in[0];
  const float* prot_x         = (const float*)d_in[1];
  const float* mol_edge_attr  = (const float*)d_in[2];
  const float* prot_edge_attr = (const float*)d_in[3];
  const float* inm_w = (const float*)d_in[4];
  const float* inm_b = (const float*)d_in[5];
  const float* inp_w = (const float*)d_in[6];
  const float* inp_b = (const float*)d_in[7];
  const float* iem_w = (const float*)d_in[8];
  const float* iem_b = (const float*)d_in[9];
  const float* iep_w = (const float*)d_in[10];
  const float* iep_b = (const float*)d_in[11];
  const float* gm_w1 = (const float*)d_in[12];
  const float* gm_b1 = (const float*)d_in[13];
  const float* gm_w2 = (const float*)d_in[14];
  const float* gm_b2 = (const float*)d_in[15];
  const float* gp_w1 = (const float*)d_in[16];
  const float* gp_b1 = (const float*)d_in[17];
  const float* gp_w2 = (const float*)d_in[18];
  const float* gp_b2 = (const float*)d_in[19];
  const float* m2p_w = (const float*)d_in[20];
  const float* m2p_b = (const float*)d_in[21];
  const float* p2m_w = (const float*)d_in[22];
  const float* p2m_b = (const float*)d_in[23];
  const float* lnm_g = (const float*)d_in[24];
  const float* lnm_b = (const float*)d_in[25];
  const float* lnp_g = (const float*)d_in[26];
  const float* lnp_b = (const float*)d_in[27];
  const float* fc1_w = (const float*)d_in[28];
  const float* fc1_b = (const float*)d_in[29];
  const float* fc2_w = (const float*)d_in[30];
  const float* fc2_b = (const float*)d_in[31];
  const int* mol_ei     = (const int*)d_in[32];
  const int* prot_ei    = (const int*)d_in[33];
  const int* mol_batch  = (const int*)d_in[34];
  const int* prot_batch = (const int*)d_in[35];

  const int NM = 4096, NP = 8192, EM = 65536, EP = 262144;

  float* ws = (float*)d_ws;
  size_t off = 0;
  auto nxt  = [&](size_t n) { float* p = ws + off; off += n; return p; };
  auto nxtH = [&](size_t n) { _Float16* p = (_Float16*)(ws + off); off += (n + 1) / 2; return p; };
  float* x_mol    = nxt((size_t)NM * 64);
  float* x_prot   = nxt((size_t)NP * 64);
  float* agg_mol  = nxt((size_t)NM * 64);   // agg_mol/agg_prot contiguous:
  float* agg_prot = nxt((size_t)NP * 64);   // single memset covers both
  float* h_mol    = nxt((size_t)NM * 64);
  float* h_prot   = nxt((size_t)NP * 64);
  _Float16* Qm  = nxtH((size_t)NM * 64);
  _Float16* Km  = nxtH((size_t)NM * 64);
  _Float16* Vtm = nxtH((size_t)NM * 64);
  _Float16* Qp  = nxtH((size_t)NP * 64);
  _Float16* Kp  = nxtH((size_t)NP * 64);
  _Float16* Vtp = nxtH((size_t)NP * 64);
  float* OPm = nxt((size_t)NSPLIT * NM * 64);  // attn partial O (mol queries)
  float* LPm = nxt((size_t)NSPLIT * NM * 4);   // attn partial L
  float* OPp = nxt((size_t)NSPLIT * NP * 64);
  float* LPp = nxt((size_t)NSPLIT * NP * 4);
  float* pool = nxt(32 * 128);
  float* cnt  = nxt(64);

  init_embed_kernel<<<NM * 64 / 256, 256, 0, stream>>>(mol_x, inm_w, inm_b, x_mol, NM, 11);
  init_embed_kernel<<<NP * 64 / 256, 256, 0, stream>>>(prot_x, inp_w, inp_b, x_prot, NP, 15);

  for (int l = 0; l < 3; l++) {
    (void)hipMemsetAsync(agg_mol, 0, (size_t)(NM + NP) * 64 * 4, stream);
    gine_msg_dual<<<(EM + EP) * 64 / 256, 256, 0, stream>>>(
        x_mol, mol_edge_attr, iem_w, iem_b, mol_ei, agg_mol, EM,
        x_prot, prot_edge_attr, iep_w, iep_b, prot_ei, agg_prot, EP);
    gine_mlp_dual<<<192, 256, 0, stream>>>(
        x_mol, agg_mol, gm_w1 + l * 4096, gm_b1 + l * 64, gm_w2 + l * 4096, gm_b2 + l * 64, h_mol,
        x_prot, agg_prot, gp_w1 + l * 4096, gp_b1 + l * 64, gp_w2 + l * 4096, gp_b2 + l * 64, h_prot);
    // m2p: Q=mol (m2p W0), K/V=prot (m2p W1,W2); p2m: Q=prot (p2m W0), K/V=mol (p2m W1,W2)
    proj_qkv_dual<<<192, 256, 0, stream>>>(
        h_mol,
        m2p_w + (l * 3 + 0) * 4096, m2p_b + (l * 3 + 0) * 64,
        p2m_w + (l * 3 + 1) * 4096, p2m_b + (l * 3 + 1) * 64,
        p2m_w + (l * 3 + 2) * 4096, p2m_b + (l * 3 + 2) * 64,
        Qm, Km, Vtm,
        h_prot,
        p2m_w + (l * 3 + 0) * 4096, p2m_b + (l * 3 + 0) * 64,
        m2p_w + (l * 3 + 1) * 4096, m2p_b + (l * 3 + 1) * 64,
        m2p_w + (l * 3 + 2) * 4096, m2p_b + (l * 3 + 2) * 64,
        Qp, Kp, Vtp);
    attn_split_kernel<<<dim3(NM / 64, 4, NSPLIT), 256, 0, stream>>>(Qm, Kp, Vtp, OPm, LPm, NM, NP);
    attn_split_kernel<<<dim3(NP / 64, 4, NSPLIT), 256, 0, stream>>>(Qp, Km, Vtm, OPp, LPp, NP, NM);
    ln_combine_dual<<<(NM + NP) * 64 / 256, 256, 0, stream>>>(
        h_mol, OPm, LPm, lnm_g + l * 64, lnm_b + l * 64, x_mol, NM,
        h_prot, OPp, LPp, lnp_g + l * 64, lnp_b + l * 64, x_prot, NP);
  }

  (void)hipMemsetAsync(pool, 0, (32 * 128 + 64) * 4, stream);  // pool+cnt contiguous
  pool_run_kernel<<<48, 256, 0, stream>>>(x_mol, mol_batch, x_prot, prot_batch, pool, cnt);
  final_kernel<<<1, 256, 0, stream>>>(pool, cnt, fc1_w, fc1_b, fc2_w, fc2_b, (float*)d_out);
}